// Round 6
// baseline (144.433 us; speedup 1.0000x reference)
//
#include <hip/hip_runtime.h>

// Problem constants (reference: B,T,D,O = 16,1024,1024,10; T==D required)
#define BB 16
#define TT 1024
#define DD 1024
#define OO 10

// ---------------------------------------------------------------------------
// Shared GEMM for both passes:
//   Y[b][o][t] = (sum_d X[b][t][d] * Wsel[o][d] + bias[o]) * scale
// Wsel = Wt (shared, K1) or Wt + b*O*D (per-batch w_x, K3).
//
// R5 post-mortem: every prior version had wave-instructions whose lanes
// touched 8 rows 4 KB apart (same L1 sets -> conflict evictions -> every x
// read = L2/HBM round trip). Fix: stage x tiles through LDS so every global
// load instruction is CONTIGUOUS (512 B from one row per 32 lanes).
//
// Mapping: grid (T/32, B), block 256 = 4 waves, 32 rows/block, D chunked 128.
//  - W (40 KB) staged to LDS once (contiguous float4).
//  - Per chunk c: block stages 32 rows x 128 floats (16.9 KB padded) into
//    LDS double buffer. Thread stages 4 float4: f = k*256+tid -> row f/32,
//    col4 f%32 (contiguous per wave-instr).
//  - Compute: lane = g*8+l of wave w; group g owns rows g+8j (j=0..3);
//    reads x float4 at chunk col4 = w*8+l (LDS, pad +1 float4/row) and
//    W float4 (8-address broadcast, cheap). 40 float4-fma per chunk.
//  - One __syncthreads per chunk (write next buf, compute cur, barrier);
//    global loads for c+1 issued first so FMAs hide their latency.
//  - 8-lane dot -> 3 __shfl_down(width=8), cross-wave combine via 5 KB LDS.
// LDS total 78 KB -> 2 blocks/CU. R2 lesson: no occupancy hint, chunk loop
// unroll 1.
// ---------------------------------------------------------------------------
template <bool BIAS>
__global__ __launch_bounds__(256) void gemm10_kernel(
    const float* __restrict__ X,   // (B,T,D)
    const float* __restrict__ Wt,  // (O,D) or (B,O,D)
    const float* __restrict__ bias,
    float* __restrict__ Y,         // (B,O,T)
    float scale, int perBatchW)
{
    __shared__ float4 sW4[OO * 256];     // 40 KB: W[o][d] as float4
    __shared__ float4 sX[2][32 * 33];    // 2 x 16.9 KB: row*33 + col4 (pad)
    __shared__ float  part[4][32][OO];   // 5 KB

    const int b   = blockIdx.y;
    const int t0  = blockIdx.x * 32;
    const int tid = threadIdx.x;

    // ---- stage W -> LDS (contiguous float4) ----
    {
        const float4* src = (const float4*)(Wt + (size_t)(perBatchW ? b : 0) * (OO * DD));
#pragma unroll
        for (int c = 0; c < 10; ++c)
            sW4[c * 256 + tid] = src[c * 256 + tid];
    }

    // staging map: thread stages 4 float4 per chunk, contiguous per wave-instr
    const int srow = tid >> 5;          // + 8k
    const int scol = tid & 31;
    const float4* Xb = (const float4*)(X + ((size_t)b * TT + t0) * DD);
    // row r, chunk c, col4 q -> Xb[r*256 + c*32 + q]

    // prologue: chunk 0 into buffer 0
    {
        float4 st[4];
#pragma unroll
        for (int k = 0; k < 4; ++k)
            st[k] = Xb[(size_t)(srow + 8 * k) * 256 + scol];
#pragma unroll
        for (int k = 0; k < 4; ++k)
            sX[0][(srow + 8 * k) * 33 + scol] = st[k];
    }
    __syncthreads();   // covers W staging too

    const int w    = tid >> 6;       // wave -> col4 slice within chunk
    const int lane = tid & 63;
    const int l    = lane & 7;
    const int g    = lane >> 3;
    const int xoff = w * 8 + l;      // col4 within the 32-float4 chunk

    float acc[4][OO];
#pragma unroll
    for (int j = 0; j < 4; ++j)
#pragma unroll
        for (int o = 0; o < OO; ++o) acc[j][o] = 0.f;

#pragma unroll 1
    for (int c = 0; c < 8; ++c) {
        float4 st[4];
        if (c < 7) {                 // issue next chunk's global loads FIRST
#pragma unroll
            for (int k = 0; k < 4; ++k)
                st[k] = Xb[(size_t)(srow + 8 * k) * 256 + (c + 1) * 32 + scol];
        }

        // compute chunk c from LDS
        const float4* xb = sX[c & 1];
        float4 xf[4];
#pragma unroll
        for (int j = 0; j < 4; ++j)
            xf[j] = xb[(g + 8 * j) * 33 + xoff];
#pragma unroll
        for (int o = 0; o < OO; ++o) {
            const float4 wv = sW4[o * 256 + c * 32 + xoff];
#pragma unroll
            for (int j = 0; j < 4; ++j)
                acc[j][o] += xf[j].x * wv.x + xf[j].y * wv.y +
                             xf[j].z * wv.z + xf[j].w * wv.w;
        }

        if (c < 7) {                 // write next chunk into the other buffer
#pragma unroll
            for (int k = 0; k < 4; ++k)
                sX[(c + 1) & 1][(srow + 8 * k) * 33 + scol] = st[k];
        }
        __syncthreads();
    }

    // 3-level reduction within each 8-lane group, then cross-wave via LDS.
#pragma unroll
    for (int j = 0; j < 4; ++j) {
#pragma unroll
        for (int o = 0; o < OO; ++o) {
            float v = acc[j][o];
            v += __shfl_down(v, 4, 8);
            v += __shfl_down(v, 2, 8);
            v += __shfl_down(v, 1, 8);
            if (l == 0) part[w][j * 8 + g][o] = v;
        }
    }
    __syncthreads();

    // 32 rows x 10 o = 320 outputs
    for (int idx = tid; idx < 32 * OO; idx += 256) {
        const int row = idx / OO;
        const int o   = idx % OO;
        float v = part[0][row][o] + part[1][row][o] +
                  part[2][row][o] + part[3][row][o];
        if (BIAS) v = (v + bias[o]) * scale;
        Y[((size_t)b * OO + o) * TT + (t0 + row)] = v;
    }
}

// ---------------------------------------------------------------------------
// K2: in-place softmax along T for each (b,o) column (contiguous, length 1024).
// ---------------------------------------------------------------------------
__global__ __launch_bounds__(256) void softmax_kernel(float* __restrict__ s)
{
    float* col = s + (size_t)blockIdx.x * TT;
    const int tid  = threadIdx.x;
    const int wave = tid >> 6;
    const int lane = tid & 63;

    float4 v = *(const float4*)(col + tid * 4);

    __shared__ float sm[4];
    __shared__ float ss[4];

    float m = fmaxf(fmaxf(v.x, v.y), fmaxf(v.z, v.w));
#pragma unroll
    for (int off = 32; off > 0; off >>= 1) m = fmaxf(m, __shfl_down(m, off, 64));
    if (lane == 0) sm[wave] = m;
    __syncthreads();
    m = fmaxf(fmaxf(sm[0], sm[1]), fmaxf(sm[2], sm[3]));

    float e0 = __expf(v.x - m), e1 = __expf(v.y - m);
    float e2 = __expf(v.z - m), e3 = __expf(v.w - m);
    float sum = e0 + e1 + e2 + e3;
#pragma unroll
    for (int off = 32; off > 0; off >>= 1) sum += __shfl_down(sum, off, 64);
    if (lane == 0) ss[wave] = sum;
    __syncthreads();
    const float inv = 1.0f / (ss[0] + ss[1] + ss[2] + ss[3]);

    *(float4*)(col + tid * 4) = make_float4(e0 * inv, e1 * inv, e2 * inv, e3 * inv);
}

extern "C" void kernel_launch(void* const* d_in, const int* in_sizes, int n_in,
                              void* d_out, int out_size, void* d_ws, size_t ws_size,
                              hipStream_t stream)
{
    const float* logits = (const float*)d_in[0];
    // d_in[1] = decision — unused by the forward math
    const float* W    = (const float*)d_in[2];
    const float* bias = (const float*)d_in[3];
    float* out    = (float*)d_out;
    float* scores = (float*)d_ws;  // B*O*T floats = 655 KB (softmax in-place)

    dim3 grid(TT / 32, BB);
    // K1: scores[b][o][t] = (logits[b,t,:] . W[o,:] + bias[o]) / O
    gemm10_kernel<true><<<grid, 256, 0, stream>>>(logits, W, bias, scores,
                                                  1.0f / OO, 0);
    // K2: softmax over t for each (b,o)
    softmax_kernel<<<BB * OO, 256, 0, stream>>>(scores);
    // K3: out[b][o][t] = logits[b,t,:] . w_x[b,:,o]  (w_x stored as (B,O,T))
    gemm10_kernel<false><<<grid, 256, 0, stream>>>(logits, scores, nullptr, out,
                                                   1.0f, 1);
}